// Round 9
// baseline (2344.354 us; speedup 1.0000x reference)
//
#include <hip/hip_runtime.h>

typedef unsigned short u16;
typedef __bf16 bf16x8 __attribute__((ext_vector_type(8)));
typedef float f32x4 __attribute__((ext_vector_type(4)));
typedef u16 u16x8 __attribute__((ext_vector_type(8)));

#define BB 128
#define NN 200
#define CC 1024
#define HH 16
#define HID 4096

__device__ __forceinline__ float bf2f(u16 u) {
  union { unsigned int i; float f; } x; x.i = ((unsigned int)u) << 16; return x.f;
}
__device__ __forceinline__ u16 f2bf(float f) {
  unsigned int i = __float_as_uint(f);
  unsigned int r = (i + 0x7fffu + ((i >> 16) & 1u)) >> 16;
  return (u16)r;
}

__device__ __forceinline__ void gld_lds16(const void* g, void* l) {
  __builtin_amdgcn_global_load_lds(
      (const __attribute__((address_space(1))) void*)g,
      (__attribute__((address_space(3))) void*)l, 16, 0, 0);
}

// ---------------- weight transpose + bf16 convert: W[K][Nc] -> Wt[Nc][K] ----
__global__ __launch_bounds__(256)
void transpose_bf16(const float* __restrict__ W, u16* __restrict__ Wt, int K, int Nc) {
  __shared__ float tile[32][33];
  const int n0 = blockIdx.x * 32, k0 = blockIdx.y * 32;
  const int tx = threadIdx.x & 31, ty = threadIdx.x >> 5;   // 32 x 8
  #pragma unroll
  for (int i = 0; i < 32; i += 8)
    tile[ty + i][tx] = W[(size_t)(k0 + ty + i) * Nc + n0 + tx];
  __syncthreads();
  #pragma unroll
  for (int i = 0; i < 32; i += 8)
    Wt[(size_t)(n0 + ty + i) * K + k0 + tx] = f2bf(tile[tx][ty + i]);
}

// ---------------- rope table ------------------------------------------------
__global__ void rope_init(float* __restrict__ rc, float* __restrict__ rs) {
  const int idx = blockIdx.x * 256 + threadIdx.x;   // 0..6399
  const int n = idx >> 5, i = idx & 31;
  const float inv = powf(10000.0f, -(float)(2 * i) / 64.0f);
  const float ang = (float)n * inv;
  rc[idx] = cosf(ang);
  rs[idx] = sinf(ang);
}

// ---------------- cpe1: fp32 x + dwconv -> bf16 ----------------------------
__global__ __launch_bounds__(256)
void dwconv_add_f2b(const float* __restrict__ x, const float* __restrict__ w,
                    const float* __restrict__ bs, u16* __restrict__ out) {
  const size_t bn = blockIdx.x;
  const int n = (int)(bn % NN);
  const int t = threadIdx.x;
  const int c = t * 4;
  const float4 z4 = make_float4(0.f, 0.f, 0.f, 0.f);
  float4 xc = ((const float4*)(x + bn * CC))[t];
  float4 xm = (n > 0)      ? ((const float4*)(x + (bn - 1) * CC))[t] : z4;
  float4 xp = (n < NN - 1) ? ((const float4*)(x + (bn + 1) * CC))[t] : z4;
  const float* xcp = (const float*)&xc;
  const float* xmp = (const float*)&xm;
  const float* xpp = (const float*)&xp;
  ushort4 o; u16* op = (u16*)&o;
  #pragma unroll
  for (int j = 0; j < 4; ++j) {
    const int ch = c + j;
    op[j] = f2bf(xcp[j] + bs[ch] + xmp[j] * w[ch * 3] + xcp[j] * w[ch * 3 + 1] + xpp[j] * w[ch * 3 + 2]);
  }
  ((ushort4*)(out + bn * CC))[t] = o;
}

// ---------------- cpe2: bf16 x + dwconv -> bf16 ----------------------------
__global__ __launch_bounds__(256)
void dwconv_add_b2b(const u16* __restrict__ x, const float* __restrict__ w,
                    const float* __restrict__ bs, u16* __restrict__ out) {
  const size_t bn = blockIdx.x;
  const int n = (int)(bn % NN);
  const int t = threadIdx.x;
  const int c = t * 4;
  const ushort4 z4 = make_ushort4(0, 0, 0, 0);
  ushort4 uc = ((const ushort4*)(x + bn * CC))[t];
  ushort4 um = (n > 0)      ? ((const ushort4*)(x + (bn - 1) * CC))[t] : z4;
  ushort4 up = (n < NN - 1) ? ((const ushort4*)(x + (bn + 1) * CC))[t] : z4;
  const u16* ucp = (const u16*)&uc;
  const u16* ump = (const u16*)&um;
  const u16* upp = (const u16*)&up;
  ushort4 o; u16* op = (u16*)&o;
  #pragma unroll
  for (int j = 0; j < 4; ++j) {
    const int ch = c + j;
    const float xv = bf2f(ucp[j]);
    op[j] = f2bf(xv + bs[ch] + bf2f(ump[j]) * w[ch * 3] + xv * w[ch * 3 + 1] + bf2f(upp[j]) * w[ch * 3 + 2]);
  }
  ((ushort4*)(out + bn * CC))[t] = o;
}

// ---------------- dwconv (bf16 in) + SiLU -> bf16 --------------------------
__global__ __launch_bounds__(256)
void dwconv_silu_bf16(const u16* __restrict__ x, const float* __restrict__ w,
                      const float* __restrict__ bs, u16* __restrict__ out) {
  const size_t bn = blockIdx.x;
  const int n = (int)(bn % NN);
  const int t = threadIdx.x;
  const int c = t * 4;
  const ushort4 z4 = make_ushort4(0, 0, 0, 0);
  ushort4 uc = ((const ushort4*)(x + bn * CC))[t];
  ushort4 um = (n > 0)      ? ((const ushort4*)(x + (bn - 1) * CC))[t] : z4;
  ushort4 up = (n < NN - 1) ? ((const ushort4*)(x + (bn + 1) * CC))[t] : z4;
  const u16* ucp = (const u16*)&uc;
  const u16* ump = (const u16*)&um;
  const u16* upp = (const u16*)&up;
  ushort4 o; u16* op = (u16*)&o;
  #pragma unroll
  for (int j = 0; j < 4; ++j) {
    const int ch = c + j;
    float v = bs[ch] + bf2f(ump[j]) * w[ch * 3] + bf2f(ucp[j]) * w[ch * 3 + 1] + bf2f(upp[j]) * w[ch * 3 + 2];
    op[j] = f2bf(v / (1.f + __expf(-v)));
  }
  ((ushort4*)(out + bn * CC))[t] = o;
}

// ---------------- LayerNorm bf16 in -> bf16 out ----------------------------
__global__ __launch_bounds__(256)
void ln_b2b(const u16* __restrict__ x, const float* __restrict__ g,
            const float* __restrict__ bta, u16* __restrict__ out) {
  const size_t row = blockIdx.x;
  const int t = threadIdx.x;
  ushort4 u = ((const ushort4*)(x + row * CC))[t];
  const float v0 = bf2f(u.x), v1 = bf2f(u.y), v2 = bf2f(u.z), v3 = bf2f(u.w);
  float s = v0 + v1 + v2 + v3;
  float ss = v0 * v0 + v1 * v1 + v2 * v2 + v3 * v3;
  #pragma unroll
  for (int off = 32; off; off >>= 1) { s += __shfl_down(s, off); ss += __shfl_down(ss, off); }
  __shared__ float r0[4], r1[4];
  const int wv = t >> 6, ln = t & 63;
  if (ln == 0) { r0[wv] = s; r1[wv] = ss; }
  __syncthreads();
  s = r0[0] + r0[1] + r0[2] + r0[3];
  ss = r1[0] + r1[1] + r1[2] + r1[3];
  const float mean = s * (1.f / CC);
  const float var = ss * (1.f / CC) - mean * mean;
  const float rstd = rsqrtf(var + 1e-5f);
  const float4 gv = ((const float4*)g)[t];
  const float4 bv = ((const float4*)bta)[t];
  ushort4 o;
  o.x = f2bf((v0 - mean) * rstd * gv.x + bv.x);
  o.y = f2bf((v1 - mean) * rstd * gv.y + bv.y);
  o.z = f2bf((v2 - mean) * rstd * gv.z + bv.z);
  o.w = f2bf((v3 - mean) * rstd * gv.w + bv.w);
  ((ushort4*)(out + row * CC))[t] = o;
}

// ---------------- bf16 MFMA GEMM: out = epi(A[M,K] @ Wt[Nc,K]^T + bias) ----
// EPI: 1=silu->bf16, 2=bias->bf16, 3=elu+1->bf16, 5=gelu->bf16,
//      6=+res(bf16)->bf16, 7=+res(bf16)->fp32
template<int EPI>
__global__ __launch_bounds__(256)
void gemm_bf16(const u16* __restrict__ A, const u16* __restrict__ Bt,
               const float* __restrict__ bias, const u16* __restrict__ res,
               void* __restrict__ outp, int Nc, int K) {
  __shared__ u16 As[128 * 32];
  __shared__ u16 Bs[128 * 32];
  const int tid = threadIdx.x;
  const int wv = tid >> 6, ln = tid & 63;
  const int wm = (wv >> 1) * 64, wn = (wv & 1) * 64;
  const long m0 = (long)blockIdx.y * 128;
  const long n0 = (long)blockIdx.x * 128;
  f32x4 acc[4][4];
  #pragma unroll
  for (int i = 0; i < 4; ++i)
    #pragma unroll
    for (int j = 0; j < 4; ++j) acc[i][j] = (f32x4){0.f, 0.f, 0.f, 0.f};

  const int fr = ln & 15, fq = ln >> 4;
  const u16* a_base = &As[(wm + fr) * 32 + fq * 8];
  const u16* b_base = &Bs[(wn + fr) * 32 + fq * 8];
  const u16* Ag = A + (size_t)m0 * K;
  const u16* Bg = Bt + (size_t)n0 * K;

  for (int kt = 0; kt < K; kt += 32) {
    #pragma unroll
    for (int i = 0; i < 2; ++i) {
      const int cb = wv * 64 + i * 256;      // wave-uniform chunk base
      const int c = cb + ln;
      const int r = c >> 2;
      const int co = (c & 3) * 8;
      gld_lds16(Ag + (size_t)r * K + kt + co, (char*)As + (size_t)cb * 16);
      gld_lds16(Bg + (size_t)r * K + kt + co, (char*)Bs + (size_t)cb * 16);
    }
    __syncthreads();
    bf16x8 af[4], bfm[4];
    #pragma unroll
    for (int mi = 0; mi < 4; ++mi) af[mi] = *(const bf16x8*)(a_base + mi * 16 * 32);
    #pragma unroll
    for (int ni = 0; ni < 4; ++ni) bfm[ni] = *(const bf16x8*)(b_base + ni * 16 * 32);
    #pragma unroll
    for (int mi = 0; mi < 4; ++mi)
      #pragma unroll
      for (int ni = 0; ni < 4; ++ni)
        acc[mi][ni] = __builtin_amdgcn_mfma_f32_16x16x32_bf16(af[mi], bfm[ni], acc[mi][ni], 0, 0, 0);
    __syncthreads();
  }

  float* of = (float*)outp;
  u16* ob = (u16*)outp;
  const long crow = m0 + wm + fq * 4;
  #pragma unroll
  for (int mi = 0; mi < 4; ++mi) {
    #pragma unroll
    for (int ni = 0; ni < 4; ++ni) {
      const long col = n0 + wn + ni * 16 + fr;
      const float bv = bias[col];
      #pragma unroll
      for (int r = 0; r < 4; ++r) {
        const long row = crow + mi * 16 + r;
        const size_t idx = (size_t)row * Nc + col;
        float v = acc[mi][ni][r] + bv;
        if constexpr (EPI == 1) ob[idx] = f2bf(v / (1.f + __expf(-v)));
        else if constexpr (EPI == 2) ob[idx] = f2bf(v);
        else if constexpr (EPI == 3) ob[idx] = f2bf(v > 0.f ? v + 1.f : __expf(v));
        else if constexpr (EPI == 5) ob[idx] = f2bf(0.5f * v * (1.f + erff(v * 0.70710678118654752f)));
        else if constexpr (EPI == 6) ob[idx] = f2bf(v + bf2f(res[idx]));
        else if constexpr (EPI == 7) of[idx] = v + bf2f(res[idx]);
      }
    }
  }
}

// ---------------- ksum[b,h,d] = mean_n k[b,n,h,d] (chunk-local) ------------
__global__ __launch_bounds__(256)
void ksum_kernel(const u16* __restrict__ Kc, float* __restrict__ ks) {
  const int bh = blockIdx.x, b = bh >> 4, h = bh & 15;
  const int t = threadIdx.x, wv = t >> 6, d = t & 63;
  const u16* base = Kc + (size_t)b * NN * CC + h * 64 + d;
  float acc = 0.f;
  for (int n = wv; n < NN; n += 4) acc += bf2f(base[(size_t)n * CC]);
  __shared__ float red[4][64];
  red[wv][d] = acc;
  __syncthreads();
  if (wv == 0)
    ks[(size_t)bh * 64 + d] = (red[0][d] + red[1][d] + red[2][d] + red[3][d]) * (1.f / NN);
}

// ---------------- kv[b,h,d,e] = (1/N) sum_n rope(k)[n,d] * v[n,e] ----------
__global__ __launch_bounds__(256)
void kv_kernel(const u16* __restrict__ Kc, const u16* __restrict__ Hc,
               const float* __restrict__ rc, const float* __restrict__ rs,
               float* __restrict__ kv) {
  const int bh = blockIdx.x, b = bh >> 4, h = bh & 15;
  __shared__ float Ks[64][64];
  __shared__ float Vs[64][64];
  const int t = threadIdx.x;
  const int e0 = (t & 15) * 4, d0 = (t >> 4) * 4;
  const u16* Kbase = Kc + (size_t)b * NN * CC + h * 64;
  const u16* Vbase = Hc + (size_t)b * NN * CC + h * 64;
  float acc[4][4] = {};
  for (int c0 = 0; c0 < NN; c0 += 64) {
    #pragma unroll
    for (int i = 0; i < 8; ++i) {
      const int idx = t + i * 256;          // 0..2047
      const int nn = idx >> 5, pr = idx & 31;
      const int n = c0 + nn;
      float k0 = 0.f, k1 = 0.f, v0 = 0.f, v1 = 0.f;
      if (n < NN) {
        const ushort2 kk = *(const ushort2*)(Kbase + (size_t)n * CC + pr * 2);
        const ushort2 vv = *(const ushort2*)(Vbase + (size_t)n * CC + pr * 2);
        const float cc = rc[n * 32 + pr], sn = rs[n * 32 + pr];
        const float ka = bf2f(kk.x), kb = bf2f(kk.y);
        k0 = ka * cc - kb * sn;
        k1 = ka * sn + kb * cc;
        v0 = bf2f(vv.x); v1 = bf2f(vv.y);
      }
      Ks[nn][pr * 2] = k0; Ks[nn][pr * 2 + 1] = k1;
      Vs[nn][pr * 2] = v0; Vs[nn][pr * 2 + 1] = v1;
    }
    __syncthreads();
    #pragma unroll 4
    for (int nn = 0; nn < 64; ++nn) {
      const float4 kk = *(const float4*)&Ks[nn][d0];
      const float4 vv = *(const float4*)&Vs[nn][e0];
      const float* kp = (const float*)&kk;
      const float* vp = (const float*)&vv;
      #pragma unroll
      for (int di = 0; di < 4; ++di)
        #pragma unroll
        for (int ej = 0; ej < 4; ++ej) acc[di][ej] += kp[di] * vp[ej];
    }
    __syncthreads();
  }
  float* o = kv + (size_t)bh * 4096;
  #pragma unroll
  for (int di = 0; di < 4; ++di)
    #pragma unroll
    for (int ej = 0; ej < 4; ++ej)
      o[(d0 + di) * 64 + e0 + ej] = acc[di][ej] * (1.f / NN);
}

// ---------------- o = (rope(q) @ kv) * z + lepe(Hc), * act -> bf16 ----------
__global__ __launch_bounds__(256)
void o_kernel(const u16* __restrict__ Qc, const u16* __restrict__ Hc,
              const u16* __restrict__ ACT,
              const float* __restrict__ rc, const float* __restrict__ rs,
              const float* __restrict__ kvg, const float* __restrict__ ksum,
              const float* __restrict__ lw, const float* __restrict__ lb,
              u16* __restrict__ outp) {
  const int bh = blockIdx.x, b = bh >> 4, h = bh & 15;
  __shared__ float KVs[64 * 64];
  __shared__ float Qs[64][64];
  __shared__ float KSs[64];
  __shared__ float Z[64];
  const int t = threadIdx.x;
  const float* kvp = kvg + (size_t)bh * 4096;
  #pragma unroll
  for (int i = 0; i < 16; ++i) KVs[t + i * 256] = kvp[t + i * 256];
  if (t < 64) KSs[t] = ksum[(size_t)bh * 64 + t];
  const u16* Qbase = Qc + (size_t)b * NN * CC + h * 64;
  const int wv = t >> 6, ln = t & 63;
  const int nn = t >> 2, sg = (t & 3) * 16;
  const int e0 = (t & 15) * 4, nr0 = (t >> 4) * 4;

  for (int c0 = 0; c0 < NN; c0 += 64) {
    const int n = c0 + nn;
    float qv[16];
    if (n < NN) {
      const u16* qp = Qbase + (size_t)n * CC + sg;
      const u16x8 q0 = *(const u16x8*)qp;
      const u16x8 q1 = *(const u16x8*)(qp + 8);
      #pragma unroll
      for (int j = 0; j < 8; ++j) { qv[j] = bf2f(q0[j]); qv[8 + j] = bf2f(q1[j]); }
    } else {
      #pragma unroll
      for (int j = 0; j < 16; ++j) qv[j] = 0.f;
    }
    #pragma unroll
    for (int j = 0; j < 16; ++j) Qs[nn][sg + j] = qv[j];
    __syncthreads();
    // z = 1/(q . ksum + 1e-6) (non-rope q)
    for (int rr = 0; rr < 16; ++rr) {
      const int nrow = wv * 16 + rr;
      float p = Qs[nrow][ln] * KSs[ln];
      #pragma unroll
      for (int offs = 32; offs; offs >>= 1) p += __shfl_down(p, offs);
      if (ln == 0) Z[nrow] = 1.f / (p + 1e-6f);
    }
    __syncthreads();
    // rope q in place (from registers)
    if (n < NN) {
      #pragma unroll
      for (int j = 0; j < 8; ++j) {
        const int pi = (sg >> 1) + j;
        const float cc = rc[n * 32 + pi], sn = rs[n * 32 + pi];
        const float a = qv[2 * j], bq = qv[2 * j + 1];
        Qs[nn][sg + 2 * j] = a * cc - bq * sn;
        Qs[nn][sg + 2 * j + 1] = a * sn + bq * cc;
      }
    }
    __syncthreads();
    float acc[4][4] = {};
    #pragma unroll 2
    for (int i = 0; i < 32; ++i) {
      const float4 kv0 = *(const float4*)&KVs[(2 * i) * 64 + e0];
      const float4 kv1 = *(const float4*)&KVs[(2 * i + 1) * 64 + e0];
      const float* k0p = (const float*)&kv0;
      const float* k1p = (const float*)&kv1;
      #pragma unroll
      for (int r = 0; r < 4; ++r) {
        const float2 qq = *(const float2*)&Qs[nr0 + r][2 * i];
        #pragma unroll
        for (int j = 0; j < 4; ++j) acc[r][j] += qq.x * k0p[j] + qq.y * k1p[j];
      }
    }
    #pragma unroll
    for (int r = 0; r < 4; ++r) {
      const int n2 = c0 + nr0 + r;
      if (n2 < NN) {
        const float z = Z[nr0 + r];
        const size_t rowoff = ((size_t)b * NN + n2) * CC + h * 64 + e0;
        const ushort4 zu = make_ushort4(0, 0, 0, 0);
        ushort4 a4 = *(const ushort4*)(ACT + rowoff);
        ushort4 hm = (n2 > 0)      ? *(const ushort4*)(Hc + rowoff - CC) : zu;
        ushort4 h0 = *(const ushort4*)(Hc + rowoff);
        ushort4 hp = (n2 < NN - 1) ? *(const ushort4*)(Hc + rowoff + CC) : zu;
        const u16* a4p = (const u16*)&a4;
        const u16* hmp = (const u16*)&hm;
        const u16* h0p = (const u16*)&h0;
        const u16* hpp = (const u16*)&hp;
        ushort4 ov; u16* ovp = (u16*)&ov;
        #pragma unroll
        for (int j = 0; j < 4; ++j) {
          const int ch = h * 64 + e0 + j;
          const float lep = lb[ch] + bf2f(hmp[j]) * lw[ch * 3] + bf2f(h0p[j]) * lw[ch * 3 + 1] + bf2f(hpp[j]) * lw[ch * 3 + 2];
          const float val = (acc[r][j] * z + lep) * bf2f(a4p[j]);
          ovp[j] = f2bf(val);
        }
        *(ushort4*)(outp + rowoff) = ov;
      }
    }
    __syncthreads();
  }
}

extern "C" void kernel_launch(void* const* d_in, const int* in_sizes, int n_in,
                              void* d_out, int out_size, void* d_ws, size_t ws_size,
                              hipStream_t stream) {
  const float* x      = (const float*)d_in[0];
  const float* cpe1_w = (const float*)d_in[1];
  const float* cpe1_b = (const float*)d_in[2];
  const float* cpe2_w = (const float*)d_in[3];
  const float* cpe2_b = (const float*)d_in[4];
  const float* n1g    = (const float*)d_in[5];
  const float* n1b    = (const float*)d_in[6];
  const float* n2g    = (const float*)d_in[7];
  const float* n2b    = (const float*)d_in[8];
  const float* in_w   = (const float*)d_in[9];
  const float* in_b   = (const float*)d_in[10];
  const float* out_w  = (const float*)d_in[11];
  const float* out_b  = (const float*)d_in[12];
  const float* actp_w = (const float*)d_in[13];
  const float* actp_b = (const float*)d_in[14];
  const float* dwc_w  = (const float*)d_in[15];
  const float* dwc_b  = (const float*)d_in[16];
  const float* qk_w   = (const float*)d_in[17];
  const float* qk_b   = (const float*)d_in[18];
  const float* lepe_w = (const float*)d_in[19];
  const float* lepe_b = (const float*)d_in[20];
  const float* fc1_w  = (const float*)d_in[21];
  const float* fc1_b  = (const float*)d_in[22];
  const float* fc2_w  = (const float*)d_in[23];
  const float* fc2_b  = (const float*)d_in[24];

  char* ws = (char*)d_ws;
  size_t off = 0;
  auto alloc = [&](size_t bytes) { size_t r = off; off += (bytes + 255) & ~(size_t)255; return r; };

  // ---- fixed region: rope tables + transposed bf16 weights (~26.5 MiB) ----
  float* RC   = (float*)(ws + alloc((size_t)NN * 32 * 4));
  float* RS   = (float*)(ws + alloc((size_t)NN * 32 * 4));
  u16* actp_t = (u16*)(ws + alloc((size_t)CC * CC * 2));
  u16* in_t   = (u16*)(ws + alloc((size_t)CC * CC * 2));
  u16* qk_t   = (u16*)(ws + alloc((size_t)2 * CC * CC * 2));
  u16* out_t  = (u16*)(ws + alloc((size_t)CC * CC * 2));
  u16* fc1_t  = (u16*)(ws + alloc((size_t)HID * CC * 2));
  u16* fc2_t  = (u16*)(ws + alloc((size_t)CC * HID * 2));
  const size_t fixedEnd = off;

  // ---- runtime config: largest batch-chunk layout that fits ws_size -------
  // regions: R1=S/X3, R2=XN/Q, R3=ACT/Y, R4=HIN/o_out, R5=HC, R6=K/X2,
  //          KV+KS (fp32), G (fc1 sub-chunk, GR x 4096 bf16)
  const int  bcs[6] = {128, 64, 32, 32, 16, 16};
  const long grs[6] = {4096, 4096, 4096, 2048, 2048, 1024};
  int Bc = 0; long GR = 0;
  size_t oR[6] = {0}, oKV = 0, oKS = 0, oG = 0;
  for (int c = 0; c < 6; ++c) {
    off = fixedEnd;
    const size_t u = (size_t)bcs[c] * NN * CC * 2;
    size_t r_[6];
    for (int i = 0; i < 6; ++i) r_[i] = alloc(u);
    size_t kvo = alloc((size_t)bcs[c] * HH * 64 * 64 * 4);
    size_t kso = alloc((size_t)bcs[c] * HH * 64 * 4);
    size_t go  = alloc((size_t)grs[c] * HID * 2);
    if (off <= ws_size) {
      Bc = bcs[c]; GR = grs[c];
      for (int i = 0; i < 6; ++i) oR[i] = r_[i];
      oKV = kvo; oKS = kso; oG = go;
      break;
    }
  }
  if (!Bc) return;   // ws too small even for smallest plan (~78 MB)

  u16*   bS   = (u16*)(ws + oR[0]);   // shortcut, later X3
  u16*   bXN  = (u16*)(ws + oR[1]);   // LN1 out, later Q
  u16*   bACT = (u16*)(ws + oR[2]);   // act_res, later Y (LN2 out)
  u16*   bHIN = (u16*)(ws + oR[3]);   // in-proj out, later o_out
  u16*   bHC  = (u16*)(ws + oR[4]);   // conv+silu (attn input)
  u16*   bK   = (u16*)(ws + oR[5]);   // k, later X2
  float* bKV  = (float*)(ws + oKV);
  float* bKS  = (float*)(ws + oKS);
  u16*   bG   = (u16*)(ws + oG);

  // ---- weight prep (once) -------------------------------------------------
  transpose_bf16<<<dim3(CC / 32, CC / 32), 256, 0, stream>>>(actp_w, actp_t, CC, CC);
  transpose_bf16<<<dim3(CC / 32, CC / 32), 256, 0, stream>>>(in_w, in_t, CC, CC);
  transpose_bf16<<<dim3(2 * CC / 32, CC / 32), 256, 0, stream>>>(qk_w, qk_t, CC, 2 * CC);
  transpose_bf16<<<dim3(CC / 32, CC / 32), 256, 0, stream>>>(out_w, out_t, CC, CC);
  transpose_bf16<<<dim3(HID / 32, CC / 32), 256, 0, stream>>>(fc1_w, fc1_t, CC, HID);
  transpose_bf16<<<dim3(CC / 32, HID / 32), 256, 0, stream>>>(fc2_w, fc2_t, HID, CC);
  rope_init<<<25, 256, 0, stream>>>(RC, RS);

  // ---- per-batch-chunk pipeline (block is exactly per-batch separable) ----
  const int nCh = BB / Bc;
  for (int ch = 0; ch < nCh; ++ch) {
    const long rowBase = (long)ch * Bc * NN;
    const long Mc = (long)Bc * NN;
    const int  mt = (int)(Mc / 128);
    const float* xC = x + (size_t)rowBase * CC;

    // s = x + cpe1(x)
    dwconv_add_f2b<<<Mc, 256, 0, stream>>>(xC, cpe1_w, cpe1_b, bS);
    // xn = LN1(s)
    ln_b2b<<<Mc, 256, 0, stream>>>(bS, n1g, n1b, bXN);
    // act = silu(xn @ actp_w + b)
    gemm_bf16<1><<<dim3(8, mt), 256, 0, stream>>>(bXN, actp_t, actp_b, nullptr, bACT, CC, CC);
    // h = xn @ in_w + b
    gemm_bf16<2><<<dim3(8, mt), 256, 0, stream>>>(bXN, in_t, in_b, nullptr, bHIN, CC, CC);
    // hc = silu(dwc(h))
    dwconv_silu_bf16<<<Mc, 256, 0, stream>>>(bHIN, dwc_w, dwc_b, bHC);
    // q = elu(hc @ qk_w[:, :1024] + b)+1  (into R2; XN dead)
    gemm_bf16<3><<<dim3(8, mt), 256, 0, stream>>>(bHC, qk_t, qk_b, nullptr, bXN, CC, CC);
    // k = elu(hc @ qk_w[:, 1024:] + b)+1
    gemm_bf16<3><<<dim3(8, mt), 256, 0, stream>>>(bHC, qk_t + (size_t)CC * CC, qk_b + CC, nullptr, bK, CC, CC);
    // attention core
    ksum_kernel<<<Bc * HH, 256, 0, stream>>>(bK, bKS);
    kv_kernel<<<Bc * HH, 256, 0, stream>>>(bK, bHC, RC, RS, bKV);
    o_kernel<<<Bc * HH, 256, 0, stream>>>(bXN, bHC, bACT, RC, RS, bKV, bKS, lepe_w, lepe_b, bHIN);
    // x2 = s + (o*act) @ out_w + b   (into R6; K dead)
    gemm_bf16<6><<<dim3(8, mt), 256, 0, stream>>>(bHIN, out_t, out_b, bS, bK, CC, CC);
    // x3 = x2 + cpe2(x2)             (into R1; S dead)
    dwconv_add_b2b<<<Mc, 256, 0, stream>>>(bK, cpe2_w, cpe2_b, bS);
    // y = LN2(x3)                    (into R3; ACT dead)
    ln_b2b<<<Mc, 256, 0, stream>>>(bS, n2g, n2b, bACT);
    // MLP, fc1/fc2 row-sub-chunked so G never fully materializes
    for (long r0 = 0; r0 < Mc; r0 += GR) {
      const long rows = (Mc - r0 < GR) ? (Mc - r0) : GR;
      gemm_bf16<5><<<dim3(HID / 128, (int)(rows / 128)), 256, 0, stream>>>(
          bACT + (size_t)r0 * CC, fc1_t, fc1_b, nullptr, bG, HID, CC);
      gemm_bf16<7><<<dim3(8, (int)(rows / 128)), 256, 0, stream>>>(
          bG, fc2_t, fc2_b, bS + (size_t)r0 * CC,
          (float*)d_out + (size_t)(rowBase + r0) * CC, CC, HID);
    }
  }

  (void)in_sizes; (void)n_in; (void)out_size;
}